// Round 10
// baseline (409.279 us; speedup 1.0000x reference)
//
#include <hip/hip_runtime.h>
#include <hip/hip_bf16.h>
#include <math.h>

#define N_ATOMS 4096
#define N_EDGES 131072
#define PI6 0.52359877559829887308f

typedef __attribute__((ext_vector_type(4))) float f32x4;
typedef _Float16 h16;
typedef __attribute__((ext_vector_type(8))) _Float16 half8;

__device__ __forceinline__ float silu_f(float x) { return x / (1.0f + __expf(-x)); }

__device__ __forceinline__ unsigned pk2h(float lo, float hi) {
    h16 a = (h16)lo, b = (h16)hi;
    unsigned short ua, ub;
    __builtin_memcpy(&ua, &a, 2);
    __builtin_memcpy(&ub, &b, 2);
    return ((unsigned)ub << 16) | (unsigned)ua;
}

// ---------------------------------------------------------------------------
// W-prep (f32): gather W_tp (only first 64 out-cols used downstream) into
// Wsl[f][o], f = s*128+c in [0,1152), o in [0,64). row(s,c) per reference.
// ---------------------------------------------------------------------------
__global__ void wprep_kernel(const float* __restrict__ Wtp, float* __restrict__ Wsl)
{
    int idx = blockIdx.x * 256 + threadIdx.x;     // < 9*128*64 = 73728
    int o = idx & 63;
    int c = (idx >> 6) & 127;
    int s = idx >> 13;
    int row = (s == 0) ? c : (s < 4 ? 128 + c * 3 + (s - 1) : 512 + c * 5 + (s - 4));
    Wsl[idx] = Wtp[row * 128 + o];
}

// ---------------------------------------------------------------------------
// Counting sort of edges by dst.
// ---------------------------------------------------------------------------
__global__ void count_kernel(const int* __restrict__ eidx, int* __restrict__ deg)
{
    int e = blockIdx.x * 256 + threadIdx.x;
    atomicAdd(&deg[eidx[N_EDGES + e]], 1);
}

__global__ void scan_kernel(const int* __restrict__ deg, int* __restrict__ base,
                            int* __restrict__ cur)
{
    __shared__ int sums[1024];
    const int t = threadIdx.x;
    int v0 = deg[4*t], v1 = deg[4*t+1], v2 = deg[4*t+2], v3 = deg[4*t+3];
    int s = v0 + v1 + v2 + v3;
    sums[t] = s;
    __syncthreads();
    for (int off = 1; off < 1024; off <<= 1) {
        int x = (t >= off) ? sums[t - off] : 0;
        __syncthreads();
        sums[t] += x;
        __syncthreads();
    }
    int excl = (t > 0) ? sums[t - 1] : 0;
    base[4*t]   = excl;             cur[4*t]   = excl;
    base[4*t+1] = excl + v0;        cur[4*t+1] = excl + v0;
    base[4*t+2] = excl + v0 + v1;   cur[4*t+2] = excl + v0 + v1;
    base[4*t+3] = excl + v0 + v1 + v2; cur[4*t+3] = excl + v0 + v1 + v2;
}

__global__ void scatter_kernel(const int* __restrict__ eidx, int* __restrict__ cur,
                               int* __restrict__ sortedE)
{
    int e = blockIdx.x * 256 + threadIdx.x;
    int dst = eidx[N_EDGES + e];
    int p = atomicAdd(&cur[dst], 1);
    sortedE[p] = e;
}

// ---------------------------------------------------------------------------
// Aggregation kernel: one block (128 thr) per dst atom, atoms
// [aoff, aoff+2048). Writes Gm[localdst][1152] (local = dst - aoff).
// 16-edge chunks: rbf/sh -> R1 -> R2 (4edge x 4chan reg tile) -> LDS
// round-trip -> G[9] per thread-channel. All f32, no atomics.
// ---------------------------------------------------------------------------
__global__ __launch_bounds__(128) void agg_kernel(
    const float* __restrict__ evec, const float* __restrict__ elen,
    const int* __restrict__ sortedE, const int* __restrict__ base,
    const int* __restrict__ deg, int aoff,
    const float* __restrict__ Wr1, const float* __restrict__ br1,
    const float* __restrict__ Wr2, const float* __restrict__ br2,
    float* __restrict__ Gm)
{
    __shared__ __align__(16) float rbfL[16][8];
    __shared__ float shL[16][9];
    __shared__ __align__(16) float R1L[64][16];   // [j][edge]
    __shared__ __align__(16) float R2L[16][128];  // [edge][channel]

    const int t = threadIdx.x;
    const int dst = aoff + blockIdx.x;
    const int dg = deg[dst];
    const int bs = base[dst];

    const int el8 = t >> 3, f8 = t & 7;   // rbf task: 16 edges x 8 freqs
    const int e4 = t >> 5, c4 = t & 31;   // R2 task: 4-edge group x 4-chan group
    const int elR = t & 15, koR = t >> 4; // R1 task

    float G[9] = {0.f,0.f,0.f,0.f,0.f,0.f,0.f,0.f,0.f};

    const int nch = (dg + 15) >> 4;
    for (int c = 0; c < nch; ++c) {
        __syncthreads();
        // ---- rbf: all 128 threads, one (edge,freq) each ----
        {
            int ce = c * 16 + el8;
            float v = 0.f;
            if (ce < dg) {
                int eid = sortedE[bs + ce];
                float len = elen[eid];
                float env = 0.5f * (cosf(len * PI6) + 1.0f) * (len < 6.0f ? 1.0f : 0.0f);
                v = sinf(len * ((float)(f8 + 1) * PI6)) * (env / len);
            }
            rbfL[el8][f8] = v;
        }
        // ---- sh: threads 0..15, one edge each ----
        if (t < 16) {
            int ce = c * 16 + t;
            float s0=0,s1=0,s2=0,s3=0,s4=0,s5=0,s6=0,s7=0,s8=0;
            if (ce < dg) {
                int eid = sortedE[bs + ce];
                float vx = evec[eid*3], vy = evec[eid*3+1], vz = evec[eid*3+2];
                float r = sqrtf(vx*vx + vy*vy + vz*vz) + 1e-8f;
                float inv = 1.0f / r;
                float x = vx*inv, y = vy*inv, z = vz*inv;
                s0 = 1.0f; s1 = y; s2 = z; s3 = x;
                s4 = 3.0f*z*z - 1.0f; s5 = x*z; s6 = y*z; s7 = x*y; s8 = x*x - y*y;
            }
            shL[t][0]=s0; shL[t][1]=s1; shL[t][2]=s2; shL[t][3]=s3;
            shL[t][4]=s4; shL[t][5]=s5; shL[t][6]=s6; shL[t][7]=s7; shL[t][8]=s8;
        }
        __syncthreads();
        // ---- R1: thread=(edge elR), 8 reps over ko ----
        {
            f32x4 rb0 = *(const f32x4*)&rbfL[elR][0];
            f32x4 rb1 = *(const f32x4*)&rbfL[elR][4];
            #pragma unroll
            for (int rep = 0; rep < 8; ++rep) {
                int ko = koR + rep * 8;
                float acc = br1[ko];
                acc = fmaf(rb0.x, Wr1[0*64 + ko], acc);
                acc = fmaf(rb0.y, Wr1[1*64 + ko], acc);
                acc = fmaf(rb0.z, Wr1[2*64 + ko], acc);
                acc = fmaf(rb0.w, Wr1[3*64 + ko], acc);
                acc = fmaf(rb1.x, Wr1[4*64 + ko], acc);
                acc = fmaf(rb1.y, Wr1[5*64 + ko], acc);
                acc = fmaf(rb1.z, Wr1[6*64 + ko], acc);
                acc = fmaf(rb1.w, Wr1[7*64 + ko], acc);
                R1L[ko][elR] = silu_f(acc);
            }
        }
        __syncthreads();
        // ---- R2: 4 edges x 4 channels per thread ----
        {
            f32x4 a0 = {0.f,0.f,0.f,0.f}, a1 = a0, a2 = a0, a3 = a0;
            const float* Wp = Wr2 + c4 * 4;
            #pragma unroll 4
            for (int j = 0; j < 64; ++j) {
                f32x4 r = *(const f32x4*)&R1L[j][e4 * 4];
                f32x4 w = *(const f32x4*)&Wp[j * 128];
                a0 += w * r.x;
                a1 += w * r.y;
                a2 += w * r.z;
                a3 += w * r.w;
            }
            f32x4 b2 = *(const f32x4*)&br2[c4 * 4];
            a0 += b2; a1 += b2; a2 += b2; a3 += b2;
            f32x4 o0, o1, o2, o3;
            #pragma unroll
            for (int q = 0; q < 4; ++q) {
                o0[q] = silu_f(a0[q]); o1[q] = silu_f(a1[q]);
                o2[q] = silu_f(a2[q]); o3[q] = silu_f(a3[q]);
            }
            *(f32x4*)&R2L[e4*4 + 0][c4*4] = o0;
            *(f32x4*)&R2L[e4*4 + 1][c4*4] = o1;
            *(f32x4*)&R2L[e4*4 + 2][c4*4] = o2;
            *(f32x4*)&R2L[e4*4 + 3][c4*4] = o3;
        }
        __syncthreads();
        // ---- G accumulate: thread = channel t ----
        {
            int rem = dg - c * 16; if (rem > 16) rem = 16;
            for (int el = 0; el < rem; ++el) {
                float r2 = R2L[el][t];
                #pragma unroll
                for (int s = 0; s < 9; ++s) G[s] = fmaf(shL[el][s], r2, G[s]);
            }
        }
    }

    #pragma unroll
    for (int s = 0; s < 9; ++s) Gm[blockIdx.x * 1152 + s * 128 + t] = G[s];
}

// ---------------------------------------------------------------------------
// gemm_gw: agg[aoff+m][64] = Gm[m][1152] @ Wsl[1152][64] + deg*btp,
// m in [0,2048). 32x64 tile, K staged in 9 chunks of 128. Thread-tile 2m x 4o.
// ---------------------------------------------------------------------------
__global__ __launch_bounds__(256, 2) void gemm_gw(
    const float* __restrict__ Gm, const float* __restrict__ Wsl,
    const int* __restrict__ deg, const float* __restrict__ btp, int aoff,
    float* __restrict__ agg)
{
    __shared__ __align__(16) float AT[128][32];
    __shared__ __align__(16) float Ws[128][64];
    const int t  = threadIdx.x;
    const int M0 = blockIdx.x * 32;
    const int m0 = (t & 15) * 2;
    const int o0 = (t >> 4) * 4;
    float acc[2][4] = {};

    for (int kk = 0; kk < 9; ++kk) {
        __syncthreads();
        for (int idx = t; idx < 32 * 128; idx += 256) {
            int m = idx >> 7, k = idx & 127;
            AT[k][m ^ ((k & 7) << 2)] = Gm[(M0 + m) * 1152 + kk * 128 + k];
        }
        for (int idx = t; idx < 128 * 64; idx += 256) {
            int k = idx >> 6, o = idx & 63;
            Ws[k][o] = Wsl[(kk * 128 + k) * 64 + o];
        }
        __syncthreads();
        #pragma unroll 2
        for (int k = 0; k < 128; ++k) {
            int xs = (k & 7) << 2;
            float2 a2 = *(const float2*)&AT[k][m0 ^ xs];
            float4 w4 = *(const float4*)&Ws[k][o0];
            float av[2] = {a2.x, a2.y};
            float wv[4] = {w4.x, w4.y, w4.z, w4.w};
            #pragma unroll
            for (int i = 0; i < 2; ++i)
                #pragma unroll
                for (int j = 0; j < 4; ++j)
                    acc[i][j] = fmaf(av[i], wv[j], acc[i][j]);
        }
    }

    #pragma unroll
    for (int i = 0; i < 2; ++i) {
        int m = M0 + m0 + i;
        float dgm = (float)deg[aoff + m];
        #pragma unroll
        for (int j = 0; j < 4; ++j)
            agg[(aoff + m) * 64 + o0 + j] = acc[i][j] + dgm * btp[o0 + j];
    }
}

// ---------------------------------------------------------------------------
__global__ void combined_kernel(const int* __restrict__ an,
                                const float* __restrict__ emb,
                                const float* __restrict__ agg,
                                float* __restrict__ comb)
{
    int i = blockIdx.x * 256 + threadIdx.x;
    if (i < N_ATOMS * 64) {
        int n = i >> 6, d = i & 63;
        comb[n * 128 + d]      = emb[an[n] * 64 + d];
        comb[n * 128 + 64 + d] = agg[n * 64 + d];
    }
}

// ---------------------------------------------------------------------------
template <int ACT>
__global__ __launch_bounds__(256, 2) void gemm128(
    const float* __restrict__ A, const float* __restrict__ W,
    const float* __restrict__ bias, float* __restrict__ C, int N,
    const float* __restrict__ aux1, const float* __restrict__ aux2)
{
    __shared__ __align__(16) float AT[128][64];
    __shared__ __align__(16) float Ws[128][64];
    const int t  = threadIdx.x;
    const int M0 = blockIdx.x * 64;
    const int N0 = blockIdx.y * 64;

    for (int idx = t; idx < 64 * 128; idx += 256) {
        int m = idx >> 7, k = idx & 127;
        AT[k][m ^ ((k & 15) << 2)] = A[(M0 + m) * 128 + k];
    }
    for (int idx = t; idx < 128 * 64; idx += 256) {
        int k = idx >> 6, o = idx & 63;
        Ws[k][o] = W[k * N + N0 + o];
    }
    __syncthreads();

    const int m0 = (t & 15) * 4;
    const int o0 = (t >> 4) * 4;
    float acc[4][4] = {};
    #pragma unroll 2
    for (int k = 0; k < 128; ++k) {
        int xs = (k & 15) << 2;
        float4 a4 = *(const float4*)&AT[k][m0 ^ xs];
        float4 w4 = *(const float4*)&Ws[k][o0];
        float av[4] = {a4.x, a4.y, a4.z, a4.w};
        float wv[4] = {w4.x, w4.y, w4.z, w4.w};
        #pragma unroll
        for (int i = 0; i < 4; ++i)
            #pragma unroll
            for (int j = 0; j < 4; ++j)
                acc[i][j] = fmaf(av[i], wv[j], acc[i][j]);
    }

    #pragma unroll
    for (int i = 0; i < 4; ++i) {
        int m = M0 + m0 + i;
        #pragma unroll
        for (int j = 0; j < 4; ++j) {
            int o = N0 + o0 + j;
            float v = acc[i][j] + bias[o];
            if (ACT == 1) v = silu_f(v);
            if (ACT == 2) {
                float sg = 1.0f / (1.0f + __expf(-v));
                v = sg * aux1[m * 128 + o] + (1.0f - sg) * aux2[m * 128 + o];
            }
            C[m * N + o] = v;
        }
    }
}

// ---------------------------------------------------------------------------
// qkv f32 -> fp16 prep: Qh/Kh [h][n][32] (Q pre-scaled), VT [h][32d][4096n]
// ---------------------------------------------------------------------------
__global__ void qkprep_kernel(const float* __restrict__ qkvf,
                              h16* __restrict__ Qh, h16* __restrict__ Kh)
{
    int i = blockIdx.x * 256 + threadIdx.x;       // < 4*4096*32
    int d = i & 31, n = (i >> 5) & 4095, h = i >> 17;
    Qh[(h * 4096 + n) * 32 + d] = (h16)(qkvf[n * 384 + h * 32 + d] * 0.17677669529663687f);
    Kh[(h * 4096 + n) * 32 + d] = (h16)(qkvf[n * 384 + 128 + h * 32 + d]);
}

__global__ void vtprep_kernel(const float* __restrict__ qkvf,
                              h16* __restrict__ VT)
{
    int i = blockIdx.x * 256 + threadIdx.x;       // < 128*4096
    int n = i & 4095, dh = i >> 12;               // dh = h*32+d
    VT[dh * 4096 + n] = (h16)qkvf[n * 384 + 256 + dh];
}

// ---------------------------------------------------------------------------
// Flash attention, fp16 MFMA, LDS-free main loop (validated R8).
// Block = (head, 16-row q-tile); 4 waves split KV 4-way; LDS merge at end.
// ---------------------------------------------------------------------------
__global__ __launch_bounds__(256, 4) void attn_kernel(
    const h16* __restrict__ Qh, const h16* __restrict__ Kh,
    const h16* __restrict__ VT, float* __restrict__ attd)
{
    __shared__ float st[4][64][10];
    const int t = threadIdx.x, w = t >> 6, lane = t & 63;
    const int h = blockIdx.x >> 8, qt = blockIdx.x & 255;
    const int l15 = lane & 15, g = lane >> 4;

    const h16* Kb = Kh + (size_t)h * 4096 * 32;
    const h16* Vb = VT + (size_t)h * 32 * 4096;
    half8 Qf = *(const half8*)(Qh + ((size_t)(h * 4096 + qt * 16 + l15) * 32 + g * 8));

    float m = -1e30f, l = 0.0f;
    f32x4 O0 = {0.f,0.f,0.f,0.f}, O1 = {0.f,0.f,0.f,0.f};
    const f32x4 zf = {0.f,0.f,0.f,0.f};
    const int sAlane = l15 + ((g & 1) << 5);
    const bool hi = g >= 2;

    const int kvbase = w * 1024;
    for (int kt = 0; kt < 32; ++kt) {
        int kv0 = kvbase + kt * 32;
        half8 K0 = *(const half8*)(Kb + ((size_t)(kv0 + l15) * 32 + g * 8));
        half8 K1 = *(const half8*)(Kb + ((size_t)(kv0 + 16 + l15) * 32 + g * 8));
        f32x4 S0 = __builtin_amdgcn_mfma_f32_16x16x32_f16(K0, Qf, zf, 0, 0, 0);
        f32x4 S1 = __builtin_amdgcn_mfma_f32_16x16x32_f16(K1, Qf, zf, 0, 0, 0);

        float tmax = fmaxf(fmaxf(fmaxf(S0.x, S0.y), fmaxf(S0.z, S0.w)),
                           fmaxf(fmaxf(S1.x, S1.y), fmaxf(S1.z, S1.w)));
        tmax = fmaxf(tmax, __shfl_xor(tmax, 16));
        tmax = fmaxf(tmax, __shfl_xor(tmax, 32));
        float mn = fmaxf(m, tmax);
        float c = __expf(m - mn);
        m = mn;
        float p0[4], p1[4];
        float ts = 0.f;
        #pragma unroll
        for (int i = 0; i < 4; ++i) { p0[i] = __expf(S0[i] - mn); ts += p0[i]; }
        #pragma unroll
        for (int i = 0; i < 4; ++i) { p1[i] = __expf(S1[i] - mn); ts += p1[i]; }
        ts += __shfl_xor(ts, 16);
        ts += __shfl_xor(ts, 32);
        l = l * c + ts;
        #pragma unroll
        for (int i = 0; i < 4; ++i) { O0[i] *= c; O1[i] *= c; }

        unsigned A0 = pk2h(p0[0], p0[1]), A1 = pk2h(p0[2], p0[3]);
        unsigned A2 = pk2h(p1[0], p1[1]), A3 = pk2h(p1[2], p1[3]);
        unsigned t0 = (unsigned)__shfl((int)A0, sAlane);
        unsigned t1 = (unsigned)__shfl((int)A1, sAlane);
        unsigned t2 = (unsigned)__shfl((int)A2, sAlane);
        unsigned t3 = (unsigned)__shfl((int)A3, sAlane);
        unsigned u0 = (unsigned)__shfl((int)A0, sAlane + 16);
        unsigned u1 = (unsigned)__shfl((int)A1, sAlane + 16);
        unsigned u2 = (unsigned)__shfl((int)A2, sAlane + 16);
        unsigned u3 = (unsigned)__shfl((int)A3, sAlane + 16);
        union { unsigned u[4]; half8 v; } P;
        P.u[0] = hi ? t2 : t0;
        P.u[1] = hi ? t3 : t1;
        P.u[2] = hi ? u2 : u0;
        P.u[3] = hi ? u3 : u1;

        half8 V0 = *(const half8*)(Vb + ((size_t)l15 * 4096 + kv0 + g * 8));
        half8 V1 = *(const half8*)(Vb + ((size_t)(16 + l15) * 4096 + kv0 + g * 8));
        O0 = __builtin_amdgcn_mfma_f32_16x16x32_f16(V0, P.v, O0, 0, 0, 0);
        O1 = __builtin_amdgcn_mfma_f32_16x16x32_f16(V1, P.v, O1, 0, 0, 0);
    }

    #pragma unroll
    for (int i = 0; i < 4; ++i) { st[w][lane][i] = O0[i]; st[w][lane][4 + i] = O1[i]; }
    st[w][lane][8] = m;
    st[w][lane][9] = l;
    __syncthreads();

    if (w == 0) {
        float M = -1e30f;
        #pragma unroll
        for (int j = 0; j < 4; ++j) M = fmaxf(M, st[j][lane][8]);
        float L = 0.f, o0[4] = {}, o1[4] = {};
        #pragma unroll
        for (int j = 0; j < 4; ++j) {
            float f = __expf(st[j][lane][8] - M);
            L += st[j][lane][9] * f;
            #pragma unroll
            for (int i = 0; i < 4; ++i) {
                o0[i] = fmaf(st[j][lane][i], f, o0[i]);
                o1[i] = fmaf(st[j][lane][4 + i], f, o1[i]);
            }
        }
        float invL = 1.0f / L;
        int nq = qt * 16 + l15;
        #pragma unroll
        for (int i = 0; i < 4; ++i) {
            attd[nq * 128 + h * 32 + g * 4 + i]      = o0[i] * invL;
            attd[nq * 128 + h * 32 + 16 + g * 4 + i] = o1[i] * invL;
        }
    }
}

// ---------------------------------------------------------------------------
extern "C" void kernel_launch(void* const* d_in, const int* in_sizes, int n_in,
                              void* d_out, int out_size, void* d_ws, size_t ws_size,
                              hipStream_t stream) {
    const int*   an    = (const int*)d_in[0];
    const int*   eidx  = (const int*)d_in[2];
    const float* evec  = (const float*)d_in[3];
    const float* elen  = (const float*)d_in[4];
    const float* emb   = (const float*)d_in[5];
    const float* Wr1   = (const float*)d_in[6];
    const float* br1   = (const float*)d_in[7];
    const float* Wr2   = (const float*)d_in[8];
    const float* br2   = (const float*)d_in[9];
    const float* Wtp   = (const float*)d_in[10];
    const float* btp   = (const float*)d_in[11];
    const float* Wm1   = (const float*)d_in[12];
    const float* bm1   = (const float*)d_in[13];
    const float* Wm2   = (const float*)d_in[14];
    const float* bm2   = (const float*)d_in[15];
    const float* Wqkv  = (const float*)d_in[16];
    const float* bqkv  = (const float*)d_in[17];
    const float* Wao   = (const float*)d_in[18];
    const float* bao   = (const float*)d_in[19];
    const float* Wg    = (const float*)d_in[20];
    const float* bg    = (const float*)d_in[21];
    const float* Wo    = (const float*)d_in[22];
    const float* bo    = (const float*)d_in[23];

    // workspace layout (floats), extent 4,456,448 f = 17.83 MB (R6-R8 proven):
    float* ws    = (float*)d_ws;
    float* agg   = ws;                       // [0, 262144)
    float* comb  = agg  + N_ATOMS * 64;      // [262144, 786432)
    float* h1    = comb + N_ATOMS * 128;     // [786432, 1310720)
    float* upd   = h1   + N_ATOMS * 128;     // [1310720, 1835008)
    float* qkvf  = upd  + N_ATOMS * 128;     // [1835008, 3407872)
    float* attd  = qkvf + N_ATOMS * 384;     // [3407872, 3932160)
    float* aob   = attd + N_ATOMS * 128;     // [3932160, 4456448)
    // time-disjoint aliases:
    float* Wsl   = aob;                      // 73728 f; used in agg phase; aob written at t13
    float* Gm    = comb;                     // PER-HALF: 2048*1152 = 2,359,296 f
                                             //  = [262144, 2621440): covers comb/h1/upd/
                                             //  qkvf-prefix, all dead until combined/m1/m2/qkv
    float* outp  = comb;                     // comb region free again after attn preps
    // sort scratch inside attd region (dead until attn writes it):
    int* deg     = (int*)attd;               // 4096
    int* base    = deg + 4096;               // 4096
    int* cur     = base + 4096;              // 4096
    int* sortedE = cur + 4096;               // 131072  (total 143360 < 524288)
    // fp16 attention operand buffers (time-disjoint):
    h16* Qhb = (h16*)comb;                   // comb dead after gemm m1
    h16* Khb = Qhb + 4 * 4096 * 32;
    h16* VTb = (h16*)h1;                     // h1 dead after gemm m2

    hipMemsetAsync(deg, 0, 4096 * sizeof(int), stream);

    count_kernel<<<512, 256, 0, stream>>>(eidx, deg);
    scan_kernel<<<1, 1024, 0, stream>>>(deg, base, cur);
    scatter_kernel<<<512, 256, 0, stream>>>(eidx, cur, sortedE);

    wprep_kernel<<<288, 256, 0, stream>>>(Wtp, Wsl);

    // agg in two half-passes so Gm (9.44 MB/half) fits the proven extent
    agg_kernel<<<2048, 128, 0, stream>>>(
        evec, elen, sortedE, base, deg, 0, Wr1, br1, Wr2, br2, Gm);
    gemm_gw<<<64, 256, 0, stream>>>(Gm, Wsl, deg, btp, 0, agg);
    agg_kernel<<<2048, 128, 0, stream>>>(
        evec, elen, sortedE, base, deg, 2048, Wr1, br1, Wr2, br2, Gm);
    gemm_gw<<<64, 256, 0, stream>>>(Gm, Wsl, deg, btp, 2048, agg);

    combined_kernel<<<(N_ATOMS * 64) / 256, 256, 0, stream>>>(an, emb, agg, comb);

    gemm128<1><<<dim3(64, 2), 256, 0, stream>>>(comb, Wm1, bm1, h1, 128, nullptr, nullptr);
    gemm128<0><<<dim3(64, 2), 256, 0, stream>>>(h1, Wm2, bm2, upd, 128, nullptr, nullptr);
    gemm128<0><<<dim3(64, 6), 256, 0, stream>>>(upd, Wqkv, bqkv, qkvf, 384, nullptr, nullptr);

    qkprep_kernel<<<2048, 256, 0, stream>>>(qkvf, Qhb, Khb);
    vtprep_kernel<<<2048, 256, 0, stream>>>(qkvf, VTb);

    attn_kernel<<<1024, 256, 0, stream>>>(Qhb, Khb, VTb, attd);

    gemm128<0><<<dim3(64, 2), 256, 0, stream>>>(attd, Wao, bao, aob, 128, nullptr, nullptr);
    gemm128<2><<<dim3(64, 2), 256, 0, stream>>>(upd, Wg, bg, outp, 128, aob, upd);
    gemm128<0><<<dim3(64, 2), 256, 0, stream>>>(outp, Wo, bo, (float*)d_out, 128, nullptr, nullptr);
}

// Round 11
// 314.963 us; speedup vs baseline: 1.2995x; 1.2995x over previous
//
#include <hip/hip_runtime.h>
#include <hip/hip_bf16.h>
#include <math.h>

#define N_ATOMS 4096
#define N_EDGES 131072
#define PI6 0.52359877559829887308f

typedef __attribute__((ext_vector_type(4))) float f32x4;
typedef _Float16 h16;
typedef __attribute__((ext_vector_type(8))) _Float16 half8;

__device__ __forceinline__ float silu_f(float x) { return x / (1.0f + __expf(-x)); }

__device__ __forceinline__ unsigned pk2h(float lo, float hi) {
    h16 a = (h16)lo, b = (h16)hi;
    unsigned short ua, ub;
    __builtin_memcpy(&ua, &a, 2);
    __builtin_memcpy(&ub, &b, 2);
    return ((unsigned)ub << 16) | (unsigned)ua;
}

// ---------------------------------------------------------------------------
// W-prep (f32): gather W_tp (only first 64 out-cols used downstream) into
// Wsl[f][o], f = s*128+c in [0,1152), o in [0,64). row(s,c) per reference.
// ---------------------------------------------------------------------------
__global__ void wprep_kernel(const float* __restrict__ Wtp, float* __restrict__ Wsl)
{
    int idx = blockIdx.x * 256 + threadIdx.x;     // < 9*128*64 = 73728
    int o = idx & 63;
    int c = (idx >> 6) & 127;
    int s = idx >> 13;
    int row = (s == 0) ? c : (s < 4 ? 128 + c * 3 + (s - 1) : 512 + c * 5 + (s - 4));
    Wsl[idx] = Wtp[row * 128 + o];
}

// ---------------------------------------------------------------------------
// Counting sort of edges by dst.
// ---------------------------------------------------------------------------
__global__ void count_kernel(const int* __restrict__ eidx, int* __restrict__ deg)
{
    int e = blockIdx.x * 256 + threadIdx.x;
    atomicAdd(&deg[eidx[N_EDGES + e]], 1);
}

__global__ void scan_kernel(const int* __restrict__ deg, int* __restrict__ base,
                            int* __restrict__ cur)
{
    __shared__ int sums[1024];
    const int t = threadIdx.x;
    int v0 = deg[4*t], v1 = deg[4*t+1], v2 = deg[4*t+2], v3 = deg[4*t+3];
    int s = v0 + v1 + v2 + v3;
    sums[t] = s;
    __syncthreads();
    for (int off = 1; off < 1024; off <<= 1) {
        int x = (t >= off) ? sums[t - off] : 0;
        __syncthreads();
        sums[t] += x;
        __syncthreads();
    }
    int excl = (t > 0) ? sums[t - 1] : 0;
    base[4*t]   = excl;             cur[4*t]   = excl;
    base[4*t+1] = excl + v0;        cur[4*t+1] = excl + v0;
    base[4*t+2] = excl + v0 + v1;   cur[4*t+2] = excl + v0 + v1;
    base[4*t+3] = excl + v0 + v1 + v2; cur[4*t+3] = excl + v0 + v1 + v2;
}

__global__ void scatter_kernel(const int* __restrict__ eidx, int* __restrict__ cur,
                               int* __restrict__ sortedE)
{
    int e = blockIdx.x * 256 + threadIdx.x;
    int dst = eidx[N_EDGES + e];
    int p = atomicAdd(&cur[dst], 1);
    sortedE[p] = e;
}

// ---------------------------------------------------------------------------
// Aggregation kernel: one block (128 thr) per dst atom, atoms
// [aoff, aoff+2048). Writes Gm[localdst][1152] (local = dst - aoff).
// 16-edge chunks: rbf/sh -> R1 -> R2 (4edge x 4chan reg tile) -> LDS
// round-trip -> G[9] per thread-channel. All f32, no atomics.
// ---------------------------------------------------------------------------
__global__ __launch_bounds__(128) void agg_kernel(
    const float* __restrict__ evec, const float* __restrict__ elen,
    const int* __restrict__ sortedE, const int* __restrict__ base,
    const int* __restrict__ deg, int aoff,
    const float* __restrict__ Wr1, const float* __restrict__ br1,
    const float* __restrict__ Wr2, const float* __restrict__ br2,
    float* __restrict__ Gm)
{
    __shared__ __align__(16) float rbfL[16][8];
    __shared__ float shL[16][9];
    __shared__ __align__(16) float R1L[64][16];   // [j][edge]
    __shared__ __align__(16) float R2L[16][128];  // [edge][channel]

    const int t = threadIdx.x;
    const int dst = aoff + blockIdx.x;
    const int dg = deg[dst];
    const int bs = base[dst];

    const int el8 = t >> 3, f8 = t & 7;   // rbf task: 16 edges x 8 freqs
    const int e4 = t >> 5, c4 = t & 31;   // R2 task: 4-edge group x 4-chan group
    const int elR = t & 15, koR = t >> 4; // R1 task

    float G[9] = {0.f,0.f,0.f,0.f,0.f,0.f,0.f,0.f,0.f};

    const int nch = (dg + 15) >> 4;
    for (int c = 0; c < nch; ++c) {
        __syncthreads();
        // ---- rbf: all 128 threads, one (edge,freq) each ----
        {
            int ce = c * 16 + el8;
            float v = 0.f;
            if (ce < dg) {
                int eid = sortedE[bs + ce];
                float len = elen[eid];
                float env = 0.5f * (cosf(len * PI6) + 1.0f) * (len < 6.0f ? 1.0f : 0.0f);
                v = sinf(len * ((float)(f8 + 1) * PI6)) * (env / len);
            }
            rbfL[el8][f8] = v;
        }
        // ---- sh: threads 0..15, one edge each ----
        if (t < 16) {
            int ce = c * 16 + t;
            float s0=0,s1=0,s2=0,s3=0,s4=0,s5=0,s6=0,s7=0,s8=0;
            if (ce < dg) {
                int eid = sortedE[bs + ce];
                float vx = evec[eid*3], vy = evec[eid*3+1], vz = evec[eid*3+2];
                float r = sqrtf(vx*vx + vy*vy + vz*vz) + 1e-8f;
                float inv = 1.0f / r;
                float x = vx*inv, y = vy*inv, z = vz*inv;
                s0 = 1.0f; s1 = y; s2 = z; s3 = x;
                s4 = 3.0f*z*z - 1.0f; s5 = x*z; s6 = y*z; s7 = x*y; s8 = x*x - y*y;
            }
            shL[t][0]=s0; shL[t][1]=s1; shL[t][2]=s2; shL[t][3]=s3;
            shL[t][4]=s4; shL[t][5]=s5; shL[t][6]=s6; shL[t][7]=s7; shL[t][8]=s8;
        }
        __syncthreads();
        // ---- R1: thread=(edge elR), 8 reps over ko ----
        {
            f32x4 rb0 = *(const f32x4*)&rbfL[elR][0];
            f32x4 rb1 = *(const f32x4*)&rbfL[elR][4];
            #pragma unroll
            for (int rep = 0; rep < 8; ++rep) {
                int ko = koR + rep * 8;
                float acc = br1[ko];
                acc = fmaf(rb0.x, Wr1[0*64 + ko], acc);
                acc = fmaf(rb0.y, Wr1[1*64 + ko], acc);
                acc = fmaf(rb0.z, Wr1[2*64 + ko], acc);
                acc = fmaf(rb0.w, Wr1[3*64 + ko], acc);
                acc = fmaf(rb1.x, Wr1[4*64 + ko], acc);
                acc = fmaf(rb1.y, Wr1[5*64 + ko], acc);
                acc = fmaf(rb1.z, Wr1[6*64 + ko], acc);
                acc = fmaf(rb1.w, Wr1[7*64 + ko], acc);
                R1L[ko][elR] = silu_f(acc);
            }
        }
        __syncthreads();
        // ---- R2: 4 edges x 4 channels per thread ----
        {
            f32x4 a0 = {0.f,0.f,0.f,0.f}, a1 = a0, a2 = a0, a3 = a0;
            const float* Wp = Wr2 + c4 * 4;
            #pragma unroll 4
            for (int j = 0; j < 64; ++j) {
                f32x4 r = *(const f32x4*)&R1L[j][e4 * 4];
                f32x4 w = *(const f32x4*)&Wp[j * 128];
                a0 += w * r.x;
                a1 += w * r.y;
                a2 += w * r.z;
                a3 += w * r.w;
            }
            f32x4 b2 = *(const f32x4*)&br2[c4 * 4];
            a0 += b2; a1 += b2; a2 += b2; a3 += b2;
            f32x4 o0, o1, o2, o3;
            #pragma unroll
            for (int q = 0; q < 4; ++q) {
                o0[q] = silu_f(a0[q]); o1[q] = silu_f(a1[q]);
                o2[q] = silu_f(a2[q]); o3[q] = silu_f(a3[q]);
            }
            *(f32x4*)&R2L[e4*4 + 0][c4*4] = o0;
            *(f32x4*)&R2L[e4*4 + 1][c4*4] = o1;
            *(f32x4*)&R2L[e4*4 + 2][c4*4] = o2;
            *(f32x4*)&R2L[e4*4 + 3][c4*4] = o3;
        }
        __syncthreads();
        // ---- G accumulate: thread = channel t ----
        {
            int rem = dg - c * 16; if (rem > 16) rem = 16;
            for (int el = 0; el < rem; ++el) {
                float r2 = R2L[el][t];
                #pragma unroll
                for (int s = 0; s < 9; ++s) G[s] = fmaf(shL[el][s], r2, G[s]);
            }
        }
    }

    #pragma unroll
    for (int s = 0; s < 9; ++s) Gm[blockIdx.x * 1152 + s * 128 + t] = G[s];
}

// ---------------------------------------------------------------------------
// gemm_gw_part: P[kk][m][o] = Gm[m][kk*128..+128) @ Wsl[kk*128..+128)[o],
// m in [0,2048), kk in [0,9). Grid (128 M-tiles of 16, 9 K-chunks).
// 256 thr, thread = (m0 = t&15, o-group o0 = (t>>4)*4). AT padded [128][17]
// for conflict-free staging writes.
// ---------------------------------------------------------------------------
__global__ __launch_bounds__(256) void gemm_gw_part(
    const float* __restrict__ Gm, const float* __restrict__ Wsl,
    float* __restrict__ P)
{
    __shared__ __align__(16) float AT[128][17];
    __shared__ __align__(16) float Ws[128][64];
    const int t  = threadIdx.x;
    const int M0 = blockIdx.x * 16;
    const int kk = blockIdx.y;

    for (int idx = t; idx < 16 * 128; idx += 256) {
        int m = idx >> 7, k = idx & 127;
        AT[k][m] = Gm[(M0 + m) * 1152 + kk * 128 + k];
    }
    for (int idx = t; idx < 128 * 64; idx += 256) {
        int k = idx >> 6, o = idx & 63;
        Ws[k][o] = Wsl[(kk * 128 + k) * 64 + o];
    }
    __syncthreads();

    const int m0 = t & 15;
    const int o0 = (t >> 4) * 4;
    f32x4 acc = {0.f, 0.f, 0.f, 0.f};
    #pragma unroll 4
    for (int k = 0; k < 128; ++k) {
        float a = AT[k][m0];
        f32x4 w = *(const f32x4*)&Ws[k][o0];
        acc += w * a;
    }
    *(f32x4*)&P[((size_t)kk * 2048 + M0 + m0) * 64 + o0] = acc;
}

// ---------------------------------------------------------------------------
// gw_reduce: agg[aoff+m][o] = sum_kk P[kk][m][o] + deg*btp. Fixed-order sum.
// ---------------------------------------------------------------------------
__global__ void gw_reduce(const float* __restrict__ P, const int* __restrict__ deg,
                          const float* __restrict__ btp, int aoff,
                          float* __restrict__ agg)
{
    int i = blockIdx.x * 256 + threadIdx.x;   // < 2048*64
    int m = i >> 6, o = i & 63;
    float s = 0.f;
    #pragma unroll
    for (int kk = 0; kk < 9; ++kk) s += P[(size_t)kk * 131072 + i];
    agg[(aoff + m) * 64 + o] = s + (float)deg[aoff + m] * btp[o];
}

// ---------------------------------------------------------------------------
__global__ void combined_kernel(const int* __restrict__ an,
                                const float* __restrict__ emb,
                                const float* __restrict__ agg,
                                float* __restrict__ comb)
{
    int i = blockIdx.x * 256 + threadIdx.x;
    if (i < N_ATOMS * 64) {
        int n = i >> 6, d = i & 63;
        comb[n * 128 + d]      = emb[an[n] * 64 + d];
        comb[n * 128 + 64 + d] = agg[n * 64 + d];
    }
}

// ---------------------------------------------------------------------------
template <int ACT>
__global__ __launch_bounds__(256, 2) void gemm128(
    const float* __restrict__ A, const float* __restrict__ W,
    const float* __restrict__ bias, float* __restrict__ C, int N,
    const float* __restrict__ aux1, const float* __restrict__ aux2)
{
    __shared__ __align__(16) float AT[128][64];
    __shared__ __align__(16) float Ws[128][64];
    const int t  = threadIdx.x;
    const int M0 = blockIdx.x * 64;
    const int N0 = blockIdx.y * 64;

    for (int idx = t; idx < 64 * 128; idx += 256) {
        int m = idx >> 7, k = idx & 127;
        AT[k][m ^ ((k & 15) << 2)] = A[(M0 + m) * 128 + k];
    }
    for (int idx = t; idx < 128 * 64; idx += 256) {
        int k = idx >> 6, o = idx & 63;
        Ws[k][o] = W[k * N + N0 + o];
    }
    __syncthreads();

    const int m0 = (t & 15) * 4;
    const int o0 = (t >> 4) * 4;
    float acc[4][4] = {};
    #pragma unroll 2
    for (int k = 0; k < 128; ++k) {
        int xs = (k & 15) << 2;
        float4 a4 = *(const float4*)&AT[k][m0 ^ xs];
        float4 w4 = *(const float4*)&Ws[k][o0];
        float av[4] = {a4.x, a4.y, a4.z, a4.w};
        float wv[4] = {w4.x, w4.y, w4.z, w4.w};
        #pragma unroll
        for (int i = 0; i < 4; ++i)
            #pragma unroll
            for (int j = 0; j < 4; ++j)
                acc[i][j] = fmaf(av[i], wv[j], acc[i][j]);
    }

    #pragma unroll
    for (int i = 0; i < 4; ++i) {
        int m = M0 + m0 + i;
        #pragma unroll
        for (int j = 0; j < 4; ++j) {
            int o = N0 + o0 + j;
            float v = acc[i][j] + bias[o];
            if (ACT == 1) v = silu_f(v);
            if (ACT == 2) {
                float sg = 1.0f / (1.0f + __expf(-v));
                v = sg * aux1[m * 128 + o] + (1.0f - sg) * aux2[m * 128 + o];
            }
            C[m * N + o] = v;
        }
    }
}

// ---------------------------------------------------------------------------
// qkv f32 -> fp16 prep: Qh/Kh [h][n][32] (Q pre-scaled), VT [h][32d][4096n]
// ---------------------------------------------------------------------------
__global__ void qkprep_kernel(const float* __restrict__ qkvf,
                              h16* __restrict__ Qh, h16* __restrict__ Kh)
{
    int i = blockIdx.x * 256 + threadIdx.x;       // < 4*4096*32
    int d = i & 31, n = (i >> 5) & 4095, h = i >> 17;
    Qh[(h * 4096 + n) * 32 + d] = (h16)(qkvf[n * 384 + h * 32 + d] * 0.17677669529663687f);
    Kh[(h * 4096 + n) * 32 + d] = (h16)(qkvf[n * 384 + 128 + h * 32 + d]);
}

__global__ void vtprep_kernel(const float* __restrict__ qkvf,
                              h16* __restrict__ VT)
{
    int i = blockIdx.x * 256 + threadIdx.x;       // < 128*4096
    int n = i & 4095, dh = i >> 12;               // dh = h*32+d
    VT[dh * 4096 + n] = (h16)qkvf[n * 384 + 256 + dh];
}

// ---------------------------------------------------------------------------
// Flash attention, fp16 MFMA, LDS-free main loop (validated R8).
// Block = (head, 16-row q-tile); 4 waves split KV 4-way; LDS merge at end.
// ---------------------------------------------------------------------------
__global__ __launch_bounds__(256, 4) void attn_kernel(
    const h16* __restrict__ Qh, const h16* __restrict__ Kh,
    const h16* __restrict__ VT, float* __restrict__ attd)
{
    __shared__ float st[4][64][10];
    const int t = threadIdx.x, w = t >> 6, lane = t & 63;
    const int h = blockIdx.x >> 8, qt = blockIdx.x & 255;
    const int l15 = lane & 15, g = lane >> 4;

    const h16* Kb = Kh + (size_t)h * 4096 * 32;
    const h16* Vb = VT + (size_t)h * 32 * 4096;
    half8 Qf = *(const half8*)(Qh + ((size_t)(h * 4096 + qt * 16 + l15) * 32 + g * 8));

    float m = -1e30f, l = 0.0f;
    f32x4 O0 = {0.f,0.f,0.f,0.f}, O1 = {0.f,0.f,0.f,0.f};
    const f32x4 zf = {0.f,0.f,0.f,0.f};
    const int sAlane = l15 + ((g & 1) << 5);
    const bool hi = g >= 2;

    const int kvbase = w * 1024;
    for (int kt = 0; kt < 32; ++kt) {
        int kv0 = kvbase + kt * 32;
        half8 K0 = *(const half8*)(Kb + ((size_t)(kv0 + l15) * 32 + g * 8));
        half8 K1 = *(const half8*)(Kb + ((size_t)(kv0 + 16 + l15) * 32 + g * 8));
        f32x4 S0 = __builtin_amdgcn_mfma_f32_16x16x32_f16(K0, Qf, zf, 0, 0, 0);
        f32x4 S1 = __builtin_amdgcn_mfma_f32_16x16x32_f16(K1, Qf, zf, 0, 0, 0);

        float tmax = fmaxf(fmaxf(fmaxf(S0.x, S0.y), fmaxf(S0.z, S0.w)),
                           fmaxf(fmaxf(S1.x, S1.y), fmaxf(S1.z, S1.w)));
        tmax = fmaxf(tmax, __shfl_xor(tmax, 16));
        tmax = fmaxf(tmax, __shfl_xor(tmax, 32));
        float mn = fmaxf(m, tmax);
        float c = __expf(m - mn);
        m = mn;
        float p0[4], p1[4];
        float ts = 0.f;
        #pragma unroll
        for (int i = 0; i < 4; ++i) { p0[i] = __expf(S0[i] - mn); ts += p0[i]; }
        #pragma unroll
        for (int i = 0; i < 4; ++i) { p1[i] = __expf(S1[i] - mn); ts += p1[i]; }
        ts += __shfl_xor(ts, 16);
        ts += __shfl_xor(ts, 32);
        l = l * c + ts;
        #pragma unroll
        for (int i = 0; i < 4; ++i) { O0[i] *= c; O1[i] *= c; }

        unsigned A0 = pk2h(p0[0], p0[1]), A1 = pk2h(p0[2], p0[3]);
        unsigned A2 = pk2h(p1[0], p1[1]), A3 = pk2h(p1[2], p1[3]);
        unsigned t0 = (unsigned)__shfl((int)A0, sAlane);
        unsigned t1 = (unsigned)__shfl((int)A1, sAlane);
        unsigned t2 = (unsigned)__shfl((int)A2, sAlane);
        unsigned t3 = (unsigned)__shfl((int)A3, sAlane);
        unsigned u0 = (unsigned)__shfl((int)A0, sAlane + 16);
        unsigned u1 = (unsigned)__shfl((int)A1, sAlane + 16);
        unsigned u2 = (unsigned)__shfl((int)A2, sAlane + 16);
        unsigned u3 = (unsigned)__shfl((int)A3, sAlane + 16);
        union { unsigned u[4]; half8 v; } P;
        P.u[0] = hi ? t2 : t0;
        P.u[1] = hi ? t3 : t1;
        P.u[2] = hi ? u2 : u0;
        P.u[3] = hi ? u3 : u1;

        half8 V0 = *(const half8*)(Vb + ((size_t)l15 * 4096 + kv0 + g * 8));
        half8 V1 = *(const half8*)(Vb + ((size_t)(16 + l15) * 4096 + kv0 + g * 8));
        O0 = __builtin_amdgcn_mfma_f32_16x16x32_f16(V0, P.v, O0, 0, 0, 0);
        O1 = __builtin_amdgcn_mfma_f32_16x16x32_f16(V1, P.v, O1, 0, 0, 0);
    }

    #pragma unroll
    for (int i = 0; i < 4; ++i) { st[w][lane][i] = O0[i]; st[w][lane][4 + i] = O1[i]; }
    st[w][lane][8] = m;
    st[w][lane][9] = l;
    __syncthreads();

    if (w == 0) {
        float M = -1e30f;
        #pragma unroll
        for (int j = 0; j < 4; ++j) M = fmaxf(M, st[j][lane][8]);
        float L = 0.f, o0[4] = {}, o1[4] = {};
        #pragma unroll
        for (int j = 0; j < 4; ++j) {
            float f = __expf(st[j][lane][8] - M);
            L += st[j][lane][9] * f;
            #pragma unroll
            for (int i = 0; i < 4; ++i) {
                o0[i] = fmaf(st[j][lane][i], f, o0[i]);
                o1[i] = fmaf(st[j][lane][4 + i], f, o1[i]);
            }
        }
        float invL = 1.0f / L;
        int nq = qt * 16 + l15;
        #pragma unroll
        for (int i = 0; i < 4; ++i) {
            attd[nq * 128 + h * 32 + g * 4 + i]      = o0[i] * invL;
            attd[nq * 128 + h * 32 + 16 + g * 4 + i] = o1[i] * invL;
        }
    }
}

// ---------------------------------------------------------------------------
extern "C" void kernel_launch(void* const* d_in, const int* in_sizes, int n_in,
                              void* d_out, int out_size, void* d_ws, size_t ws_size,
                              hipStream_t stream) {
    const int*   an    = (const int*)d_in[0];
    const int*   eidx  = (const int*)d_in[2];
    const float* evec  = (const float*)d_in[3];
    const float* elen  = (const float*)d_in[4];
    const float* emb   = (const float*)d_in[5];
    const float* Wr1   = (const float*)d_in[6];
    const float* br1   = (const float*)d_in[7];
    const float* Wr2   = (const float*)d_in[8];
    const float* br2   = (const float*)d_in[9];
    const float* Wtp   = (const float*)d_in[10];
    const float* btp   = (const float*)d_in[11];
    const float* Wm1   = (const float*)d_in[12];
    const float* bm1   = (const float*)d_in[13];
    const float* Wm2   = (const float*)d_in[14];
    const float* bm2   = (const float*)d_in[15];
    const float* Wqkv  = (const float*)d_in[16];
    const float* bqkv  = (const float*)d_in[17];
    const float* Wao   = (const float*)d_in[18];
    const float* bao   = (const float*)d_in[19];
    const float* Wg    = (const float*)d_in[20];
    const float* bg    = (const float*)d_in[21];
    const float* Wo    = (const float*)d_in[22];
    const float* bo    = (const float*)d_in[23];

    // workspace layout (floats), extent 4,456,448 f = 17.83 MB (R6-R10 proven):
    float* ws    = (float*)d_ws;
    float* agg   = ws;                       // [0, 262144)
    float* comb  = agg  + N_ATOMS * 64;      // [262144, 786432)
    float* h1    = comb + N_ATOMS * 128;     // [786432, 1310720)
    float* upd   = h1   + N_ATOMS * 128;     // [1310720, 1835008)
    float* qkvf  = upd  + N_ATOMS * 128;     // [1835008, 3407872)
    float* attd  = qkvf + N_ATOMS * 384;     // [3407872, 3932160)
    float* aob   = attd + N_ATOMS * 128;     // [3932160, 4456448)
    // time-disjoint aliases (liveness-audited):
    float* Wsl   = aob;                      // [3932160, 4005888); agg phase; aob written later
    int*   deg     = (int*)(aob + 73728);    // [4005888, 4009984) ints
    int*   base    = deg + 4096;
    int*   cur     = base + 4096;
    int*   sortedE = cur + 4096;             // ends 4149248 < 4456448; dead before aob write
    float* Gm    = comb;                     // per-half 2048*1152 f = [262144, 2621440)
    float* Pp    = ws + 2621440;             // 9*2048*64 f = [2621440, 3801088):
                                             //  qkvf-tail + attd-prefix, both dead in agg phase
    float* outp  = comb;                     // comb region free again after attn preps
    // fp16 attention operand buffers (time-disjoint):
    h16* Qhb = (h16*)comb;                   // comb dead after gemm m1
    h16* Khb = Qhb + 4 * 4096 * 32;
    h16* VTb = (h16*)h1;                     // h1 dead after gemm m2

    hipMemsetAsync(deg, 0, 4096 * sizeof(int), stream);

    count_kernel<<<512, 256, 0, stream>>>(eidx, deg);
    scan_kernel<<<1, 1024, 0, stream>>>(deg, base, cur);
    scatter_kernel<<<512, 256, 0, stream>>>(eidx, cur, sortedE);

    wprep_kernel<<<288, 256, 0, stream>>>(Wtp, Wsl);

    // agg in two half-passes so Gm (9.44 MB/half) fits the proven extent
    agg_kernel<<<2048, 128, 0, stream>>>(
        evec, elen, sortedE, base, deg, 0, Wr1, br1, Wr2, br2, Gm);
    gemm_gw_part<<<dim3(128, 9), 256, 0, stream>>>(Gm, Wsl, Pp);
    gw_reduce<<<512, 256, 0, stream>>>(Pp, deg, btp, 0, agg);
    agg_kernel<<<2048, 128, 0, stream>>>(
        evec, elen, sortedE, base, deg, 2048, Wr1, br1, Wr2, br2, Gm);
    gemm_gw_part<<<dim3(128, 9), 256, 0, stream>>>(Gm, Wsl, Pp);
    gw_reduce<<<512, 256, 0, stream>>>(Pp, deg, btp, 2048, agg);

    combined_kernel<<<(N_ATOMS * 64) / 256, 256, 0, stream>>>(an, emb, agg, comb);

    gemm128<1><<<dim3(64, 2), 256, 0, stream>>>(comb, Wm1, bm1, h1, 128, nullptr, nullptr);
    gemm128<0><<<dim3(64, 2), 256, 0, stream>>>(h1, Wm2, bm2, upd, 128, nullptr, nullptr);
    gemm128<0><<<dim3(64, 6), 256, 0, stream>>>(upd, Wqkv, bqkv, qkvf, 384, nullptr, nullptr);

    qkprep_kernel<<<2048, 256, 0, stream>>>(qkvf, Qhb, Khb);
    vtprep_kernel<<<2048, 256, 0, stream>>>(qkvf, VTb);

    attn_kernel<<<1024, 256, 0, stream>>>(Qhb, Khb, VTb, attd);

    gemm128<0><<<dim3(64, 2), 256, 0, stream>>>(attd, Wao, bao, aob, 128, nullptr, nullptr);
    gemm128<2><<<dim3(64, 2), 256, 0, stream>>>(upd, Wg, bg, outp, 128, aob, upd);
    gemm128<0><<<dim3(64, 2), 256, 0, stream>>>(outp, Wo, bo, (float*)d_out, 128, nullptr, nullptr);
}